// Round 2
// baseline (831.147 us; speedup 1.0000x reference)
//
#include <hip/hip_runtime.h>

// Haar DWT, reflect-pad(1,0,1,0), stride 2.
// x: (8,64,512,512) f32 -> 4 subbands each (8,64,256,256), concat flat in d_out.
//
// Output (ho,wo) window in original coords:
//   rows r0 = (ho==0) ? 1 : 2*ho-1,  r1 = 2*ho
//   cols c0 = (wo==0) ? 1 : 2*wo-1,  c1 = 2*wo
//   a=x[r0][c0] b=x[r0][c1] c=x[r1][c0] d=x[r1][c1]
//   LL=.5(a+b+c+d) LH=.5(a+b-c-d) HL=.5(-a+b-c+d) HH=.5(a-b-c+d)

#define NIMG   512               // B*C
#define WIN    512
#define HOUT   256
#define WOUT   256
#define PLANE  ((size_t)NIMG * HOUT * WOUT)   // per-subband elements

__global__ __launch_bounds__(256) void haar_dwt_kernel(
    const float* __restrict__ x, float* __restrict__ out)
{
    unsigned gid = blockIdx.x * blockDim.x + threadIdx.x;
    unsigned t   = gid & 127;            // column group: covers input cols 4t..4t+3
    unsigned ho  = (gid >> 7) & 255;     // output row
    unsigned img = gid >> 15;            // 0..511

    const float* xim = x + (size_t)img * (WIN * WIN);
    int r1 = 2 * (int)ho;
    int r0 = (ho == 0) ? 1 : (2 * (int)ho - 1);

    const float4 A = *(const float4*)(xim + (size_t)r0 * WIN + 4u * t);
    const float4 B = *(const float4*)(xim + (size_t)r1 * WIN + 4u * t);

    // carry: col 4t-1 lives in lane (t-1)'s A.w / B.w
    float pA = __shfl_up(A.w, 1);
    float pB = __shfl_up(B.w, 1);
    unsigned lane = threadIdx.x & 63u;
    if (lane == 0u && t != 0u) {
        // t == 64: wave boundary within the row; reload the single carry scalar
        pA = xim[(size_t)r0 * WIN + 4u * t - 1u];
        pB = xim[(size_t)r1 * WIN + 4u * t - 1u];
    }

    // output col wo0 = 2t
    float a0, b0, c0, d0;
    if (t == 0u) {
        // wo=0: c0 reflects to col 1, c1 = col 0
        a0 = A.y; b0 = A.x; c0 = B.y; d0 = B.x;
    } else {
        a0 = pA;  b0 = A.x; c0 = pB;  d0 = B.x;
    }
    // output col wo1 = 2t+1: cols 4t+1, 4t+2
    float a1 = A.y, b1 = A.z, c1 = B.y, d1 = B.z;

    float2 ll = { 0.5f * (a0 + b0 + c0 + d0), 0.5f * (a1 + b1 + c1 + d1) };
    float2 lh = { 0.5f * (a0 + b0 - c0 - d0), 0.5f * (a1 + b1 - c1 - d1) };
    float2 hl = { 0.5f * (-a0 + b0 - c0 + d0), 0.5f * (-a1 + b1 - c1 + d1) };
    float2 hh = { 0.5f * (a0 - b0 - c0 + d0), 0.5f * (a1 - b1 - c1 + d1) };

    size_t obase = (size_t)img * (HOUT * WOUT) + (size_t)ho * WOUT + 2u * t;
    *(float2*)(out + 0 * PLANE + obase) = ll;
    *(float2*)(out + 1 * PLANE + obase) = lh;
    *(float2*)(out + 2 * PLANE + obase) = hl;
    *(float2*)(out + 3 * PLANE + obase) = hh;
}

extern "C" void kernel_launch(void* const* d_in, const int* in_sizes, int n_in,
                              void* d_out, int out_size, void* d_ws, size_t ws_size,
                              hipStream_t stream)
{
    const float* x = (const float*)d_in[0];
    float* out = (float*)d_out;

    // total threads = NIMG * HOUT * 128 = 512*256*128 = 16,777,216
    const unsigned total = NIMG * HOUT * 128u;
    const unsigned block = 256u;
    const unsigned grid  = total / block;   // 65536
    haar_dwt_kernel<<<grid, block, 0, stream>>>(x, out);
}